// Round 7
// baseline (8949.469 us; speedup 1.0000x reference)
//
#include <hip/hip_runtime.h>
#include <hip/hip_bf16.h>
#include <math.h>

typedef unsigned short u16;
typedef __attribute__((ext_vector_type(4))) float f32x4;
typedef __attribute__((ext_vector_type(8))) short s16x8;

#define BB  512
#define TT  120
#define LAT 292
#define HH1 701
#define HH3 901
#define H1P 704
#define H3P 960
#define CH  35

// ws layout (bytes) — round-5 layout (f32 carry + f32 xp1 restored)
static const size_t O_X    = 0;                     // 512*292*4
static const size_t O_XP1  = 598016;                // 512*2112*4 (f32)
static const size_t O_H1F  = 4923392;               // 2*512*704*4
static const size_t O_H2F  = 7806976;               // 2*512*704*4
static const size_t O_H3F  = 10690560;              // 2*512*960*4
static const size_t O_H1B  = 14622720;              // 2*512*704*2
static const size_t O_H2B  = 16064512;              // 2*512*704*2
static const size_t O_H3B  = 17506304;              // 2*512*960*2
static const size_t O_WHT1 = 19472384;              // 2112*704*2
static const size_t O_WIT2 = 22446080;              // 2112*704*2
static const size_t O_WHT2 = 25419776;              // 2112*704*2
static const size_t O_WIT3 = 28393472;              // 2816*704*2
static const size_t O_WHT3 = 32358400;              // 2816*960*2
static const size_t O_WOT  = 37765120;              // 64*960*2
static const size_t O_TAB  = 37888000;              // 256*4
static const size_t ZERO_BYTES = 14548992;          // O_H1F..O_H3B end

#define DSWZ(row, g) ((((g) ^ ((row) & 7)) << 4))

static __device__ __forceinline__ u16 f2b(float f){
  union { float f; unsigned int i; } v; v.f = f;
  unsigned int x = v.i;
  return (u16)((x + 0x7FFFu + ((x >> 16) & 1u)) >> 16);
}

// ---------------- prologue: x = selu(z @ W1 + b1) ----------------
__launch_bounds__(256)
__global__ void k_selu(const float* __restrict__ z, const float* __restrict__ W1,
                       const float* __restrict__ b1, float* __restrict__ x)
{
  int idx = blockIdx.x * 256 + threadIdx.x;
  if (idx >= BB * LAT) return;
  int b = idx / LAT, i = idx - b * LAT;
  float acc = b1[i];
  const float* zr = z + (size_t)b * LAT;
  for (int k = 0; k < LAT; ++k)
    acc += zr[k] * W1[k * LAT + i];
  const float alpha = 1.6732632423543772f, scale = 1.0507009873554805f;
  x[idx] = scale * (acc > 0.f ? acc : alpha * (expf(acc) - 1.f));
}

// ---------------- prologue: xp1 = x @ Wi1 + bi1 (f32, [512][2112]) ----------------
__launch_bounds__(256)
__global__ void k_xp1(const float* __restrict__ x, const float* __restrict__ Wi1,
                      const float* __restrict__ bi1, float* __restrict__ xp1)
{
  int nb = blockIdx.x % 9, bb = blockIdx.x / 9;
  int n = nb * 256 + threadIdx.x;
  int b0 = bb * 8;
  if (n >= 2112) return;
  if (n >= 2103) { for (int r = 0; r < 8; ++r) xp1[(size_t)(b0 + r) * 2112 + n] = 0.f; return; }
  float bias = bi1[n];
  float acc[8];
  for (int r = 0; r < 8; ++r) acc[r] = bias;
  for (int k = 0; k < LAT; ++k) {
    float w = Wi1[(size_t)k * 2103 + n];
    #pragma unroll
    for (int r = 0; r < 8; ++r) acc[r] += x[(size_t)(b0 + r) * LAT + k] * w;
  }
  for (int r = 0; r < 8; ++r) xp1[(size_t)(b0 + r) * 2112 + n] = acc[r];
}

// ---------------- prologue: WT[n][k] = bf16(W[k][n]), zero-padded ----------------
__launch_bounds__(256)
__global__ void k_transpose(const float* __restrict__ W, u16* __restrict__ WT,
                            int K, int N, int Kpad, int RowsPad)
{
  int tilesN = RowsPad / 64;
  int tk = blockIdx.x / tilesN, tn = blockIdx.x % tilesN;
  int k0 = tk * 64, n0 = tn * 64;
  __shared__ u16 lds[64][72];
  int tid = threadIdx.x;
  int nl = tid & 63, q = tid >> 6;
  for (int i = 0; i < 16; ++i) {
    int kl = q * 16 + i;
    int k = k0 + kl, n = n0 + nl;
    lds[kl][nl] = (k < K && n < N) ? f2b(W[(size_t)k * N + n]) : (u16)0;
  }
  __syncthreads();
  for (int i = 0; i < 16; ++i) {
    int rl = q * 16 + i;
    WT[(size_t)(n0 + rl) * Kpad + k0 + nl] = lds[nl][rl];
  }
}

// ---------------- prologue: 256 balanced 512-thread blocks, XCD col-pinned ----
__global__ void k_maketab(unsigned int* __restrict__ tab)
{
  if (threadIdx.x != 0 || blockIdx.x != 0) return;
  for (int x = 0; x < 8; ++x) {
    for (int li = 0; li < 32; ++li) {
      unsigned v;
      if (li < 15) {            // GRU3 ksplit
        int t3 = 15 * x + li;
        v = 0xFFFF0000u | (2u << 12) | ((unsigned)(t3 & 7) << 8) | (unsigned)(t3 >> 3);
      } else if (li < 26) {     // GRU2 ksplit
        int t2 = 11 * x + (li - 15);
        v = 0xFFFF0000u | (1u << 12) | ((unsigned)(t2 & 7) << 8) | (unsigned)(t2 >> 3);
      } else if (li < 31) {     // GRU1 pairs
        int pi = 5 * x + (li - 26);
        int i0 = 2 * pi, i1 = 2 * pi + 1;
        unsigned lo = ((unsigned)(i0 & 7) << 8) | (unsigned)(i0 >> 3);
        unsigned hw = ((unsigned)(i1 & 7) << 8) | (unsigned)(i1 >> 3);
        v = lo | (hw << 16);
      } else {
        if (x < 4) {            // OUT pairs
          unsigned lo = (3u << 12) | ((unsigned)(2 * x) << 8);
          unsigned hw = (3u << 12) | ((unsigned)(2 * x + 1) << 8);
          v = lo | (hw << 16);
        } else {                // leftover GRU1 pairs
          int pi = 40 + (x - 4);
          int i0 = 2 * pi, i1 = 2 * pi + 1;
          unsigned lo = ((unsigned)(i0 & 7) << 8) | (unsigned)(i0 >> 3);
          unsigned hw = ((unsigned)(i1 & 7) << 8) | (unsigned)(i1 >> 3);
          v = lo | (hw << 16);
        }
      }
      tab[x + 8 * li] = v;
    }
  }
}

// ---------------- staged-chunk helpers (K=64 chunks, XOR-swizzled LDS) ----------------
// group LDS region layout: A tile [64 rows][8 gran of 16B] at +0 (8KB),
//                          B gate g at +8192+g*8192 (8KB each)

static __device__ __forceinline__ void ld_gru(
    const u16* __restrict__ A, int As, const u16* __restrict__ W, int Ws, int WH,
    int r0, int j0, int kbase, int ltid, int4 (&ra)[2], int4 (&rb)[6])
{
  #pragma unroll
  for (int it = 0; it < 2; ++it) {
    int gi = it * 256 + ltid;
    int r = gi >> 3, gq = gi & 7;
    ra[it] = *(const int4*)(A + (size_t)(r0 + r) * As + kbase + gq * 8);
  }
  #pragma unroll
  for (int it = 0; it < 6; ++it) {
    int gi = it * 256 + ltid;
    int gate = gi >> 9, loc = gi & 511;
    int cl = loc >> 3, gq = loc & 7;
    rb[it] = *(const int4*)(W + ((size_t)gate * WH + j0 + cl) * Ws + kbase + gq * 8);
  }
}

static __device__ __forceinline__ void st_gru(char* gb, int ltid,
                                              const int4 (&ra)[2], const int4 (&rb)[6])
{
  #pragma unroll
  for (int it = 0; it < 2; ++it) {
    int gi = it * 256 + ltid;
    int r = gi >> 3, gq = gi & 7;
    *(int4*)(gb + r * 128 + DSWZ(r, gq)) = ra[it];
  }
  #pragma unroll
  for (int it = 0; it < 6; ++it) {
    int gi = it * 256 + ltid;
    int gate = gi >> 9, loc = gi & 511;
    int cl = loc >> 3, gq = loc & 7;
    *(int4*)(gb + 8192 + gate * 8192 + cl * 128 + DSWZ(cl, gq)) = rb[it];
  }
}

template<int HACC>
static __device__ __forceinline__ void mm_gru(const char* gb, int wr, int wc, int m16, int kg,
                                              f32x4 (&acc)[4][2][2])
{
  #pragma unroll
  for (int s = 0; s < 2; ++s) {
    s16x8 af[2];
    #pragma unroll
    for (int fm = 0; fm < 2; ++fm) {
      int row = wr * 32 + fm * 16 + m16;
      af[fm] = *(const s16x8*)(gb + row * 128 + DSWZ(row, s * 4 + kg));
    }
    #pragma unroll
    for (int g = 0; g < 3; ++g) {
      #pragma unroll
      for (int fn = 0; fn < 2; ++fn) {
        int col = wc * 32 + fn * 16 + m16;
        s16x8 bf = *(const s16x8*)(gb + 8192 + g * 8192 + col * 128 + DSWZ(col, s * 4 + kg));
        const int ai = (g == 2) ? HACC : g;
        #pragma unroll
        for (int fm = 0; fm < 2; ++fm)
          acc[ai][fm][fn] = __builtin_amdgcn_mfma_f32_16x16x32_bf16(af[fm], bf, acc[ai][fm][fn], 0, 0, 0);
      }
    }
  }
}

// two-segment GRU pipeline: n0 chunks of seg0 (HACC=2), n1 of seg1 (HACC=3)
static __device__ __forceinline__ void gru_pipe(
    const u16* A0, int As0, const u16* W0, int Ws0,
    const u16* A1, int As1, const u16* W1p, int Ws1,
    int WH, int n0, int n1, int k1off,
    int r0, int j0, char* gb, int ltid, int wr, int wc, int m16, int kg,
    f32x4 (&acc)[4][2][2])
{
  const int n = n0 + n1;
  int4 ra[2], rb[6];
  if (n0 > 0) ld_gru(A0, As0, W0, Ws0, WH, r0, j0, 0, ltid, ra, rb);
  else        ld_gru(A1, As1, W1p, Ws1, WH, r0, j0, k1off, ltid, ra, rb);
  st_gru(gb, ltid, ra, rb);
  __syncthreads();
  for (int ch = 0; ch < n; ++ch) {
    const bool have = (ch + 1 < n);
    if (have) {
      int c2 = ch + 1;
      if (c2 < n0) ld_gru(A0, As0, W0, Ws0, WH, r0, j0, c2 * 64, ltid, ra, rb);
      else         ld_gru(A1, As1, W1p, Ws1, WH, r0, j0, (c2 - n0) * 64 + k1off, ltid, ra, rb);
    }
    if (ch < n0) mm_gru<2>(gb, wr, wc, m16, kg, acc);
    else         mm_gru<3>(gb, wr, wc, m16, kg, acc);
    if (have) {
      __syncthreads();
      st_gru(gb, ltid, ra, rb);
      __syncthreads();
    }
  }
}

// ---------------- wavefront step kernel: 256 blocks x 512 threads ----------------
__launch_bounds__(512)
__global__ void k_wave(int s, const unsigned int* __restrict__ tab,
    const u16* __restrict__ WhT1, const u16* __restrict__ WiT2, const u16* __restrict__ WhT2,
    const u16* __restrict__ WiT3, const u16* __restrict__ WhT3, const u16* __restrict__ WoT,
    const float* __restrict__ xp1,
    const float* __restrict__ gbh1,
    const float* __restrict__ gbi2, const float* __restrict__ gbh2,
    const float* __restrict__ gbi3, const float* __restrict__ gbh3,
    const float* __restrict__ bo,
    float* __restrict__ h1f, u16* __restrict__ h1b,
    float* __restrict__ h2f, u16* __restrict__ h2b,
    float* __restrict__ h3f, u16* __restrict__ h3b,
    float* __restrict__ out)
{
  extern __shared__ __align__(16) char smem[];      // 65536 dynamic
  const int tid  = threadIdx.x;
  const int wgrp = tid >> 8;
  const int ltid = tid & 255;
  const int lane = tid & 63;
  const int wl   = (tid >> 6) & 3;
  const int wr = wl >> 1, wc = wl & 1;
  const int m16 = lane & 15, kg = lane >> 4;
  char* gb = smem + wgrp * 32768;

  const unsigned e  = tab[blockIdx.x];
  const unsigned lo = e & 0xFFFFu, hi = e >> 16;
  const bool ksplit = (hi == 0xFFFFu);
  const unsigned item = (!ksplit && wgrp == 1) ? hi : lo;
  const int L  = (item >> 12) & 3;
  const int rr = (item >> 8) & 0xF;
  const int cc = item & 0xFF;
  const int t = s - L;
  if (t < 0 || t >= TT) return;
  const int cur = s & 1, prv = cur ^ 1;

  if (L == 3) {
    // ---- output projection + softmax (each wave-group one 64-row tile) ----
    const int r0 = rr * 64;
    const u16* Ab = h3b + (size_t)prv * BB * H3P;
    f32x4 acc2[2][2];
    { f32x4 z4 = {0.f,0.f,0.f,0.f}; for (int a=0;a<2;++a) for (int b=0;b<2;++b) acc2[a][b]=z4; }
    int4 ra[2], rb2[2];
    const int n = H3P / 64;                 // 15 chunks
    // prologue
    #pragma unroll
    for (int it = 0; it < 2; ++it) {
      int gi = it * 256 + ltid; int r = gi >> 3, gq = gi & 7;
      ra[it]  = *(const int4*)(Ab + (size_t)(r0 + r) * H3P + gq * 8);
      rb2[it] = *(const int4*)(WoT + (size_t)r * H3P + gq * 8);
    }
    #pragma unroll
    for (int it = 0; it < 2; ++it) {
      int gi = it * 256 + ltid; int r = gi >> 3, gq = gi & 7;
      *(int4*)(gb + r * 128 + DSWZ(r, gq)) = ra[it];
      *(int4*)(gb + 8192 + r * 128 + DSWZ(r, gq)) = rb2[it];
    }
    __syncthreads();
    for (int ch = 0; ch < n; ++ch) {
      const bool have = (ch + 1 < n);
      if (have) {
        int kb = (ch + 1) * 64;
        #pragma unroll
        for (int it = 0; it < 2; ++it) {
          int gi = it * 256 + ltid; int r = gi >> 3, gq = gi & 7;
          ra[it]  = *(const int4*)(Ab + (size_t)(r0 + r) * H3P + kb + gq * 8);
          rb2[it] = *(const int4*)(WoT + (size_t)r * H3P + kb + gq * 8);
        }
      }
      #pragma unroll
      for (int s2 = 0; s2 < 2; ++s2) {
        s16x8 af[2], bf[2];
        #pragma unroll
        for (int fm = 0; fm < 2; ++fm) {
          int row = wr * 32 + fm * 16 + m16;
          af[fm] = *(const s16x8*)(gb + row * 128 + DSWZ(row, s2 * 4 + kg));
        }
        #pragma unroll
        for (int fn = 0; fn < 2; ++fn) {
          int col = wc * 32 + fn * 16 + m16;
          bf[fn] = *(const s16x8*)(gb + 8192 + col * 128 + DSWZ(col, s2 * 4 + kg));
        }
        #pragma unroll
        for (int fm = 0; fm < 2; ++fm)
          #pragma unroll
          for (int fn = 0; fn < 2; ++fn)
            acc2[fm][fn] = __builtin_amdgcn_mfma_f32_16x16x32_bf16(af[fm], bf[fn], acc2[fm][fn], 0, 0, 0);
      }
      if (have) {
        __syncthreads();
        #pragma unroll
        for (int it = 0; it < 2; ++it) {
          int gi = it * 256 + ltid; int r = gi >> 3, gq = gi & 7;
          *(int4*)(gb + r * 128 + DSWZ(r, gq)) = ra[it];
          *(int4*)(gb + 8192 + r * 128 + DSWZ(r, gq)) = rb2[it];
        }
        __syncthreads();
      }
    }
    __syncthreads();
    float (*ldsL)[68] = (float (*)[68])gb;
    #pragma unroll
    for (int fn = 0; fn < 2; ++fn) {
      int col = wc * 32 + fn * 16 + m16;
      float bov = (col < CH) ? bo[col] : 0.f;
      #pragma unroll
      for (int fm = 0; fm < 2; ++fm)
        #pragma unroll
        for (int ii = 0; ii < 4; ++ii)
          ldsL[wr * 32 + fm * 16 + kg * 4 + ii][col] = acc2[fm][fn][ii] + bov;
    }
    __syncthreads();
    if (ltid < 64) {
      int b = r0 + ltid;
      float mx = -1e30f;
      for (int c2 = 0; c2 < CH; ++c2) mx = fmaxf(mx, ldsL[ltid][c2]);
      float sum = 0.f;
      for (int c2 = 0; c2 < CH; ++c2) sum += expf(ldsL[ltid][c2] - mx);
      float inv = 1.f / sum;
      size_t ob = ((size_t)b * TT + t) * CH;
      for (int c2 = 0; c2 < CH; ++c2) out[ob + c2] = expf(ldsL[ltid][c2] - mx) * inv;
    }
    return;
  }

  // ---- GRU tile config ----
  int H, HP;
  const u16 *A0 = nullptr, *W0 = nullptr, *A1 = nullptr, *W1p = nullptr;
  int As0 = 0, Ws0 = 0, As1 = 0, Ws1 = 0, n0 = 0, n1 = 0, k1off = 0;
  const float *bi = nullptr, *bh;
  float *hfP, *hfC; u16 *hbC;
  if (L == 0) {
    H = HH1; HP = H1P;
    A1 = h1b + (size_t)prv * BB * H1P; As1 = H1P; W1p = WhT1; Ws1 = H1P; n1 = 11;
    bh = gbh1;
    hfP = h1f + (size_t)prv * BB * H1P; hfC = h1f + (size_t)cur * BB * H1P;
    hbC = h1b + (size_t)cur * BB * H1P;
  } else if (L == 1) {
    H = HH1; HP = H1P;
    bi = gbi2; bh = gbh2;
    hfP = h2f + (size_t)prv * BB * H1P; hfC = h2f + (size_t)cur * BB * H1P;
    hbC = h2b + (size_t)cur * BB * H1P;
    if (wgrp == 0) { A0 = h1b + (size_t)prv * BB * H1P; As0 = H1P; W0 = WiT2; Ws0 = H1P; n0 = 11; }
    else           { A1 = h2b + (size_t)prv * BB * H1P; As1 = H1P; W1p = WhT2; Ws1 = H1P; n1 = 11; }
  } else {
    H = HH3; HP = H3P;
    bi = gbi3; bh = gbh3;
    hfP = h3f + (size_t)prv * BB * H3P; hfC = h3f + (size_t)cur * BB * H3P;
    hbC = h3b + (size_t)cur * BB * H3P;
    if (wgrp == 0) {
      A0 = h2b + (size_t)prv * BB * H1P; As0 = H1P; W0 = WiT3; Ws0 = H1P; n0 = 11;
      A1 = h3b + (size_t)prv * BB * H3P; As1 = H3P; W1p = WhT3; Ws1 = H3P; n1 = 2; k1off = 0;
    } else {
      A1 = h3b + (size_t)prv * BB * H3P; As1 = H3P; W1p = WhT3; Ws1 = H3P; n1 = 13; k1off = 128;
    }
  }
  const int r0 = rr * 64, j0 = cc * 64;

  f32x4 acc[4][2][2];
  {
    f32x4 z4 = {0.f, 0.f, 0.f, 0.f};
    for (int g = 0; g < 4; ++g) for (int a = 0; a < 2; ++a) for (int b = 0; b < 2; ++b) acc[g][a][b] = z4;
  }

  gru_pipe(A0, As0, W0, Ws0, A1, As1, W1p, Ws1, H, n0, n1, k1off,
           r0, j0, gb, ltid, wr, wc, m16, kg, acc);

  if (ksplit) {
    // cross-wave-group reduction through full 64KB LDS
    __syncthreads();
    float* red = (float*)smem;
    if (wgrp == 1) {
      float* b = red + ltid * 64;
      #pragma unroll
      for (int g = 0; g < 4; ++g)
        #pragma unroll
        for (int fm = 0; fm < 2; ++fm)
          #pragma unroll
          for (int fn = 0; fn < 2; ++fn)
            *(f32x4*)(b + ((g * 2 + fm) * 2 + fn) * 4) = acc[g][fm][fn];
    }
    __syncthreads();
    if (wgrp == 1) return;
    {
      const float* b = red + ltid * 64;
      #pragma unroll
      for (int g = 0; g < 4; ++g)
        #pragma unroll
        for (int fm = 0; fm < 2; ++fm)
          #pragma unroll
          for (int fn = 0; fn < 2; ++fn)
            acc[g][fm][fn] += *(const f32x4*)(b + ((g * 2 + fm) * 2 + fn) * 4);
    }
  }

  // ---- gate epilogue (f32 carry) ----
  #pragma unroll
  for (int fn = 0; fn < 2; ++fn) {
    int j = j0 + wc * 32 + fn * 16 + m16;
    if (j >= H) continue;
    float bhz = bh[j], bhr = bh[H + j], bhh = bh[2 * H + j];
    float biz = 0.f, bir = 0.f, bih = 0.f;
    if (L != 0) { biz = bi[j]; bir = bi[H + j]; bih = bi[2 * H + j]; }
    #pragma unroll
    for (int fm = 0; fm < 2; ++fm) {
      #pragma unroll
      for (int ii = 0; ii < 4; ++ii) {
        int row = r0 + wr * 32 + fm * 16 + kg * 4 + ii;
        float az  = acc[0][fm][fn][ii];
        float ar  = acc[1][fm][fn][ii];
        float axh = acc[2][fm][fn][ii];
        float arh = acc[3][fm][fn][ii];
        float pz, pr, xh_, rh_;
        if (L == 0) {
          const float* xr_ = xp1 + (size_t)row * 2112;
          pz  = xr_[j] + az + bhz;
          pr  = xr_[HH1 + j] + ar + bhr;
          xh_ = xr_[2 * HH1 + j];
          rh_ = arh + bhh;
        } else {
          pz  = az + biz + bhz;
          pr  = ar + bir + bhr;
          xh_ = axh + bih;
          rh_ = arh + bhh;
        }
        float zg = 1.f / (1.f + expf(-pz));
        float rg = 1.f / (1.f + expf(-pr));
        float hh = tanhf(xh_ + rg * rh_);
        float hp = hfP[(size_t)row * HP + j];
        float hn = zg * hp + (1.f - zg) * hh;
        hfC[(size_t)row * HP + j] = hn;
        hbC[(size_t)row * HP + j] = f2b(hn);
      }
    }
  }
}

// ---------------- host ----------------
extern "C" void kernel_launch(void* const* d_in, const int* in_sizes, int n_in,
                              void* d_out, int out_size, void* d_ws, size_t ws_size,
                              hipStream_t stream)
{
  const float* z    = (const float*)d_in[0];
  const float* W1   = (const float*)d_in[1];
  const float* b1   = (const float*)d_in[2];
  const float* gWi1 = (const float*)d_in[3];
  const float* gWh1 = (const float*)d_in[4];
  const float* gbi1 = (const float*)d_in[5];
  const float* gbh1 = (const float*)d_in[6];
  const float* gWi2 = (const float*)d_in[7];
  const float* gWh2 = (const float*)d_in[8];
  const float* gbi2 = (const float*)d_in[9];
  const float* gbh2 = (const float*)d_in[10];
  const float* gWi3 = (const float*)d_in[11];
  const float* gWh3 = (const float*)d_in[12];
  const float* gbi3 = (const float*)d_in[13];
  const float* gbh3 = (const float*)d_in[14];
  const float* Wo   = (const float*)d_in[15];
  const float* bo   = (const float*)d_in[16];

  char* ws = (char*)d_ws;
  float* x_f  = (float*)(ws + O_X);
  float* xp1  = (float*)(ws + O_XP1);
  float* h1f  = (float*)(ws + O_H1F);
  float* h2f  = (float*)(ws + O_H2F);
  float* h3f  = (float*)(ws + O_H3F);
  u16*   h1b  = (u16*)(ws + O_H1B);
  u16*   h2b  = (u16*)(ws + O_H2B);
  u16*   h3b  = (u16*)(ws + O_H3B);
  u16*   WhT1 = (u16*)(ws + O_WHT1);
  u16*   WiT2 = (u16*)(ws + O_WIT2);
  u16*   WhT2 = (u16*)(ws + O_WHT2);
  u16*   WiT3 = (u16*)(ws + O_WIT3);
  u16*   WhT3 = (u16*)(ws + O_WHT3);
  u16*   WoT  = (u16*)(ws + O_WOT);
  unsigned int* tab = (unsigned int*)(ws + O_TAB);

  hipMemsetAsync(ws + O_H1F, 0, ZERO_BYTES, stream);

  k_maketab<<<1, 64, 0, stream>>>(tab);
  k_selu<<<(BB * LAT + 255) / 256, 256, 0, stream>>>(z, W1, b1, x_f);
  k_xp1<<<9 * 64, 256, 0, stream>>>(x_f, gWi1, gbi1, xp1);

  k_transpose<<<11 * 33, 256, 0, stream>>>(gWh1, WhT1, 701, 2103, 704, 2112);
  k_transpose<<<11 * 33, 256, 0, stream>>>(gWi2, WiT2, 701, 2103, 704, 2112);
  k_transpose<<<11 * 33, 256, 0, stream>>>(gWh2, WhT2, 701, 2103, 704, 2112);
  k_transpose<<<11 * 44, 256, 0, stream>>>(gWi3, WiT3, 701, 2703, 704, 2816);
  k_transpose<<<15 * 44, 256, 0, stream>>>(gWh3, WhT3, 901, 2703, 960, 2816);
  k_transpose<<<15 * 1, 256, 0, stream>>>(Wo, WoT, 901, 35, 960, 64);

  for (int s = 0; s < TT + 3; ++s)
    k_wave<<<256, 512, 65536, stream>>>(s, tab, WhT1, WiT2, WhT2, WiT3, WhT3, WoT, xp1,
                                        gbh1, gbi2, gbh2, gbi3, gbh3, bo,
                                        h1f, h1b, h2f, h2b, h3f, h3b, (float*)d_out);
}

// Round 8
// 8854.494 us; speedup vs baseline: 1.0107x; 1.0107x over previous
//
#include <hip/hip_runtime.h>
#include <hip/hip_bf16.h>
#include <math.h>

typedef unsigned short u16;
typedef __attribute__((ext_vector_type(4))) float f32x4;
typedef __attribute__((ext_vector_type(8))) short s16x8;

#define BB  512
#define TT  120
#define LAT 292
#define HH1 701
#define HH3 901
#define H1P 704
#define H3P 960
#define CH  35

// ws layout (bytes)
static const size_t O_X    = 0;                     // 512*292*4
static const size_t O_XP1  = 598016;                // 512*2112*4 (f32)
static const size_t O_H1F  = 4923392;               // 2*512*704*4
static const size_t O_H2F  = 7806976;               // 2*512*704*4
static const size_t O_H3F  = 10690560;              // 2*512*960*4
static const size_t O_H1B  = 14622720;              // 2*512*704*2
static const size_t O_H2B  = 16064512;              // 2*512*704*2
static const size_t O_H3B  = 17506304;              // 2*512*960*2
static const size_t O_WHT1 = 19472384;              // 2112*704*2
static const size_t O_WIT2 = 22446080;              // 2112*704*2
static const size_t O_WHT2 = 25419776;              // 2112*704*2
static const size_t O_WIT3 = 28393472;              // 2816*704*2
static const size_t O_WHT3 = 32358400;              // 2816*960*2
static const size_t O_WOT  = 37765120;              // 64*960*2
static const size_t O_TAB  = 37888000;              // 256*4
static const size_t ZERO_BYTES = 14548992;          // O_H1F..O_H3B end

#define DSWZ(row, g) ((((g) ^ ((row) & 7)) << 4))

static __device__ __forceinline__ u16 f2b(float f){
  union { float f; unsigned int i; } v; v.f = f;
  unsigned int x = v.i;
  return (u16)((x + 0x7FFFu + ((x >> 16) & 1u)) >> 16);
}

// ---------------- prologue: x = selu(z @ W1 + b1) ----------------
__launch_bounds__(256)
__global__ void k_selu(const float* __restrict__ z, const float* __restrict__ W1,
                       const float* __restrict__ b1, float* __restrict__ x)
{
  int idx = blockIdx.x * 256 + threadIdx.x;
  if (idx >= BB * LAT) return;
  int b = idx / LAT, i = idx - b * LAT;
  float acc = b1[i];
  const float* zr = z + (size_t)b * LAT;
  for (int k = 0; k < LAT; ++k)
    acc += zr[k] * W1[k * LAT + i];
  const float alpha = 1.6732632423543772f, scale = 1.0507009873554805f;
  x[idx] = scale * (acc > 0.f ? acc : alpha * (expf(acc) - 1.f));
}

// ---------------- prologue: xp1 = x @ Wi1 + bi1 (f32, [512][2112]) ----------------
__launch_bounds__(256)
__global__ void k_xp1(const float* __restrict__ x, const float* __restrict__ Wi1,
                      const float* __restrict__ bi1, float* __restrict__ xp1)
{
  int nb = blockIdx.x % 9, bb = blockIdx.x / 9;
  int n = nb * 256 + threadIdx.x;
  int b0 = bb * 8;
  if (n >= 2112) return;
  if (n >= 2103) { for (int r = 0; r < 8; ++r) xp1[(size_t)(b0 + r) * 2112 + n] = 0.f; return; }
  float bias = bi1[n];
  float acc[8];
  for (int r = 0; r < 8; ++r) acc[r] = bias;
  for (int k = 0; k < LAT; ++k) {
    float w = Wi1[(size_t)k * 2103 + n];
    #pragma unroll
    for (int r = 0; r < 8; ++r) acc[r] += x[(size_t)(b0 + r) * LAT + k] * w;
  }
  for (int r = 0; r < 8; ++r) xp1[(size_t)(b0 + r) * 2112 + n] = acc[r];
}

// ---------------- prologue: WT[n][k] = bf16(W[k][n]), zero-padded ----------------
__launch_bounds__(256)
__global__ void k_transpose(const float* __restrict__ W, u16* __restrict__ WT,
                            int K, int N, int Kpad, int RowsPad)
{
  int tilesN = RowsPad / 64;
  int tk = blockIdx.x / tilesN, tn = blockIdx.x % tilesN;
  int k0 = tk * 64, n0 = tn * 64;
  __shared__ u16 lds[64][72];
  int tid = threadIdx.x;
  int nl = tid & 63, q = tid >> 6;
  for (int i = 0; i < 16; ++i) {
    int kl = q * 16 + i;
    int k = k0 + kl, n = n0 + nl;
    lds[kl][nl] = (k < K && n < N) ? f2b(W[(size_t)k * N + n]) : (u16)0;
  }
  __syncthreads();
  for (int i = 0; i < 16; ++i) {
    int rl = q * 16 + i;
    WT[(size_t)(n0 + rl) * Kpad + k0 + nl] = lds[nl][rl];
  }
}

// ---------------- prologue: 256 balanced 512-thread blocks, XCD col-pinned ----
__global__ void k_maketab(unsigned int* __restrict__ tab)
{
  if (threadIdx.x != 0 || blockIdx.x != 0) return;
  for (int x = 0; x < 8; ++x) {
    for (int li = 0; li < 32; ++li) {
      unsigned v;
      if (li < 15) {            // GRU3 ksplit
        int t3 = 15 * x + li;
        v = 0xFFFF0000u | (2u << 12) | ((unsigned)(t3 & 7) << 8) | (unsigned)(t3 >> 3);
      } else if (li < 26) {     // GRU2 ksplit
        int t2 = 11 * x + (li - 15);
        v = 0xFFFF0000u | (1u << 12) | ((unsigned)(t2 & 7) << 8) | (unsigned)(t2 >> 3);
      } else if (li < 31) {     // GRU1 pairs
        int pi = 5 * x + (li - 26);
        int i0 = 2 * pi, i1 = 2 * pi + 1;
        unsigned lo = ((unsigned)(i0 & 7) << 8) | (unsigned)(i0 >> 3);
        unsigned hw = ((unsigned)(i1 & 7) << 8) | (unsigned)(i1 >> 3);
        v = lo | (hw << 16);
      } else {
        if (x < 4) {            // OUT pairs
          unsigned lo = (3u << 12) | ((unsigned)(2 * x) << 8);
          unsigned hw = (3u << 12) | ((unsigned)(2 * x + 1) << 8);
          v = lo | (hw << 16);
        } else {                // leftover GRU1 pairs
          int pi = 40 + (x - 4);
          int i0 = 2 * pi, i1 = 2 * pi + 1;
          unsigned lo = ((unsigned)(i0 & 7) << 8) | (unsigned)(i0 >> 3);
          unsigned hw = ((unsigned)(i1 & 7) << 8) | (unsigned)(i1 >> 3);
          v = lo | (hw << 16);
        }
      }
      tab[x + 8 * li] = v;
    }
  }
}

// ---------------- staged-chunk helpers (K=64 chunks, XOR-swizzled LDS) ----------------
// buffer layout (32KB): A tile [64 rows][8 gran of 16B] at +0 (8KB),
//                       B gate g at +8192+g*8192 (8KB each)

static __device__ __forceinline__ void ld_gru(
    const u16* __restrict__ A, int As, const u16* __restrict__ W, int Ws, int WH,
    int r0, int j0, int kbase, int ltid, int4 (&ra)[2], int4 (&rb)[6])
{
  #pragma unroll
  for (int it = 0; it < 2; ++it) {
    int gi = it * 256 + ltid;
    int r = gi >> 3, gq = gi & 7;
    ra[it] = *(const int4*)(A + (size_t)(r0 + r) * As + kbase + gq * 8);
  }
  #pragma unroll
  for (int it = 0; it < 6; ++it) {
    int gi = it * 256 + ltid;
    int gate = gi >> 9, loc = gi & 511;
    int cl = loc >> 3, gq = loc & 7;
    rb[it] = *(const int4*)(W + ((size_t)gate * WH + j0 + cl) * Ws + kbase + gq * 8);
  }
}

static __device__ __forceinline__ void st_gru(char* gb, int ltid,
                                              const int4 (&ra)[2], const int4 (&rb)[6])
{
  #pragma unroll
  for (int it = 0; it < 2; ++it) {
    int gi = it * 256 + ltid;
    int r = gi >> 3, gq = gi & 7;
    *(int4*)(gb + r * 128 + DSWZ(r, gq)) = ra[it];
  }
  #pragma unroll
  for (int it = 0; it < 6; ++it) {
    int gi = it * 256 + ltid;
    int gate = gi >> 9, loc = gi & 511;
    int cl = loc >> 3, gq = loc & 7;
    *(int4*)(gb + 8192 + gate * 8192 + cl * 128 + DSWZ(cl, gq)) = rb[it];
  }
}

template<int HACC>
static __device__ __forceinline__ void mm_gru(const char* gb, int wr, int wc, int m16, int kg,
                                              f32x4 (&acc)[4][2][2])
{
  #pragma unroll
  for (int s = 0; s < 2; ++s) {
    s16x8 af[2];
    #pragma unroll
    for (int fm = 0; fm < 2; ++fm) {
      int row = wr * 32 + fm * 16 + m16;
      af[fm] = *(const s16x8*)(gb + row * 128 + DSWZ(row, s * 4 + kg));
    }
    #pragma unroll
    for (int g = 0; g < 3; ++g) {
      #pragma unroll
      for (int fn = 0; fn < 2; ++fn) {
        int col = wc * 32 + fn * 16 + m16;
        s16x8 bf = *(const s16x8*)(gb + 8192 + g * 8192 + col * 128 + DSWZ(col, s * 4 + kg));
        const int ai = (g == 2) ? HACC : g;
        #pragma unroll
        for (int fm = 0; fm < 2; ++fm)
          acc[ai][fm][fn] = __builtin_amdgcn_mfma_f32_16x16x32_bf16(af[fm], bf, acc[ai][fm][fn], 0, 0, 0);
      }
    }
  }
}

// two-segment GRU pipeline: double-buffered LDS, ONE barrier per chunk
static __device__ __forceinline__ void gru_pipe(
    const u16* A0, int As0, const u16* W0, int Ws0,
    const u16* A1, int As1, const u16* W1p, int Ws1,
    int WH, int n0, int n1, int k1off,
    int r0, int j0, char* g0, char* g1, int ltid, int wr, int wc, int m16, int kg,
    f32x4 (&acc)[4][2][2])
{
  const int n = n0 + n1;
  int4 ra[2], rb[6];
#define LDC(C) do { int c_ = (C); \
    if (c_ < n0) ld_gru(A0, As0, W0, Ws0, WH, r0, j0, c_ * 64, ltid, ra, rb); \
    else         ld_gru(A1, As1, W1p, Ws1, WH, r0, j0, (c_ - n0) * 64 + k1off, ltid, ra, rb); \
  } while (0)
  LDC(0);
  st_gru(g0, ltid, ra, rb);
  __syncthreads();
  for (int ch = 0; ch < n; ch += 2) {
    const bool h1 = (ch + 1 < n);
    if (h1) LDC(ch + 1);
    if (ch < n0) mm_gru<2>(g0, wr, wc, m16, kg, acc);
    else         mm_gru<3>(g0, wr, wc, m16, kg, acc);
    if (!h1) break;
    st_gru(g1, ltid, ra, rb);
    __syncthreads();
    const bool h2 = (ch + 2 < n);
    if (h2) LDC(ch + 2);
    if (ch + 1 < n0) mm_gru<2>(g1, wr, wc, m16, kg, acc);
    else             mm_gru<3>(g1, wr, wc, m16, kg, acc);
    if (!h2) break;
    st_gru(g0, ltid, ra, rb);
    __syncthreads();
  }
#undef LDC
}

// ---------------- wavefront step kernel: 256 blocks x 512 threads, 128KB LDS ----------------
__launch_bounds__(512, 2)
__global__ void k_wave(int s, const unsigned int* __restrict__ tab,
    const u16* __restrict__ WhT1, const u16* __restrict__ WiT2, const u16* __restrict__ WhT2,
    const u16* __restrict__ WiT3, const u16* __restrict__ WhT3, const u16* __restrict__ WoT,
    const float* __restrict__ xp1,
    const float* __restrict__ gbh1,
    const float* __restrict__ gbi2, const float* __restrict__ gbh2,
    const float* __restrict__ gbi3, const float* __restrict__ gbh3,
    const float* __restrict__ bo,
    float* __restrict__ h1f, u16* __restrict__ h1b,
    float* __restrict__ h2f, u16* __restrict__ h2b,
    float* __restrict__ h3f, u16* __restrict__ h3b,
    float* __restrict__ out)
{
  extern __shared__ __align__(16) char smem[];      // 131072 dynamic
  const int tid  = threadIdx.x;
  const int wgrp = tid >> 8;
  const int ltid = tid & 255;
  const int lane = tid & 63;
  const int wl   = (tid >> 6) & 3;
  const int wr = wl >> 1, wc = wl & 1;
  const int m16 = lane & 15, kg = lane >> 4;
  char* g0 = smem + wgrp * 65536;
  char* g1 = g0 + 32768;

  const unsigned e  = tab[blockIdx.x];
  const unsigned lo = e & 0xFFFFu, hi = e >> 16;
  const bool ksplit = (hi == 0xFFFFu);
  const unsigned item = (!ksplit && wgrp == 1) ? hi : lo;
  const int L  = (item >> 12) & 3;
  const int rr = (item >> 8) & 0xF;
  const int cc = item & 0xFF;
  const int t = s - L;
  if (t < 0 || t >= TT) return;
  const int cur = s & 1, prv = cur ^ 1;

  if (L == 3) {
    // ---- output projection + softmax (each wave-group one 64-row tile) ----
    const int r0 = rr * 64;
    const u16* Ab = h3b + (size_t)prv * BB * H3P;
    f32x4 acc2[2][2];
    { f32x4 z4 = {0.f,0.f,0.f,0.f}; for (int a=0;a<2;++a) for (int b=0;b<2;++b) acc2[a][b]=z4; }
    int4 ra[2], rb2[2];
    const int n = H3P / 64;                 // 15 chunks
    #pragma unroll
    for (int it = 0; it < 2; ++it) {
      int gi = it * 256 + ltid; int r = gi >> 3, gq = gi & 7;
      ra[it]  = *(const int4*)(Ab + (size_t)(r0 + r) * H3P + gq * 8);
      rb2[it] = *(const int4*)(WoT + (size_t)r * H3P + gq * 8);
    }
    #pragma unroll
    for (int it = 0; it < 2; ++it) {
      int gi = it * 256 + ltid; int r = gi >> 3, gq = gi & 7;
      *(int4*)(g0 + r * 128 + DSWZ(r, gq)) = ra[it];
      *(int4*)(g0 + 8192 + r * 128 + DSWZ(r, gq)) = rb2[it];
    }
    __syncthreads();
    for (int ch = 0; ch < n; ++ch) {
      const bool have = (ch + 1 < n);
      if (have) {
        int kb = (ch + 1) * 64;
        #pragma unroll
        for (int it = 0; it < 2; ++it) {
          int gi = it * 256 + ltid; int r = gi >> 3, gq = gi & 7;
          ra[it]  = *(const int4*)(Ab + (size_t)(r0 + r) * H3P + kb + gq * 8);
          rb2[it] = *(const int4*)(WoT + (size_t)r * H3P + kb + gq * 8);
        }
      }
      #pragma unroll
      for (int s2 = 0; s2 < 2; ++s2) {
        s16x8 af[2], bf[2];
        #pragma unroll
        for (int fm = 0; fm < 2; ++fm) {
          int row = wr * 32 + fm * 16 + m16;
          af[fm] = *(const s16x8*)(g0 + row * 128 + DSWZ(row, s2 * 4 + kg));
        }
        #pragma unroll
        for (int fn = 0; fn < 2; ++fn) {
          int col = wc * 32 + fn * 16 + m16;
          bf[fn] = *(const s16x8*)(g0 + 8192 + col * 128 + DSWZ(col, s2 * 4 + kg));
        }
        #pragma unroll
        for (int fm = 0; fm < 2; ++fm)
          #pragma unroll
          for (int fn = 0; fn < 2; ++fn)
            acc2[fm][fn] = __builtin_amdgcn_mfma_f32_16x16x32_bf16(af[fm], bf[fn], acc2[fm][fn], 0, 0, 0);
      }
      if (have) {
        __syncthreads();
        #pragma unroll
        for (int it = 0; it < 2; ++it) {
          int gi = it * 256 + ltid; int r = gi >> 3, gq = gi & 7;
          *(int4*)(g0 + r * 128 + DSWZ(r, gq)) = ra[it];
          *(int4*)(g0 + 8192 + r * 128 + DSWZ(r, gq)) = rb2[it];
        }
        __syncthreads();
      }
    }
    __syncthreads();
    float (*ldsL)[68] = (float (*)[68])g0;
    #pragma unroll
    for (int fn = 0; fn < 2; ++fn) {
      int col = wc * 32 + fn * 16 + m16;
      float bov = (col < CH) ? bo[col] : 0.f;
      #pragma unroll
      for (int fm = 0; fm < 2; ++fm)
        #pragma unroll
        for (int ii = 0; ii < 4; ++ii)
          ldsL[wr * 32 + fm * 16 + kg * 4 + ii][col] = acc2[fm][fn][ii] + bov;
    }
    __syncthreads();
    if (ltid < 64) {
      int b = r0 + ltid;
      float mx = -1e30f;
      for (int c2 = 0; c2 < CH; ++c2) mx = fmaxf(mx, ldsL[ltid][c2]);
      float sum = 0.f;
      for (int c2 = 0; c2 < CH; ++c2) sum += expf(ldsL[ltid][c2] - mx);
      float inv = 1.f / sum;
      size_t ob = ((size_t)b * TT + t) * CH;
      for (int c2 = 0; c2 < CH; ++c2) out[ob + c2] = expf(ldsL[ltid][c2] - mx) * inv;
    }
    return;
  }

  // ---- GRU tile config ----
  int H, HP;
  const u16 *A0 = nullptr, *W0 = nullptr, *A1 = nullptr, *W1p = nullptr;
  int As0 = 0, Ws0 = 0, As1 = 0, Ws1 = 0, n0 = 0, n1 = 0, k1off = 0;
  const float *bi = nullptr, *bh;
  float *hfP, *hfC; u16 *hbC;
  if (L == 0) {
    H = HH1; HP = H1P;
    A1 = h1b + (size_t)prv * BB * H1P; As1 = H1P; W1p = WhT1; Ws1 = H1P; n1 = 11;
    bh = gbh1;
    hfP = h1f + (size_t)prv * BB * H1P; hfC = h1f + (size_t)cur * BB * H1P;
    hbC = h1b + (size_t)cur * BB * H1P;
  } else if (L == 1) {
    H = HH1; HP = H1P;
    bi = gbi2; bh = gbh2;
    hfP = h2f + (size_t)prv * BB * H1P; hfC = h2f + (size_t)cur * BB * H1P;
    hbC = h2b + (size_t)cur * BB * H1P;
    if (wgrp == 0) { A0 = h1b + (size_t)prv * BB * H1P; As0 = H1P; W0 = WiT2; Ws0 = H1P; n0 = 11; }
    else           { A1 = h2b + (size_t)prv * BB * H1P; As1 = H1P; W1p = WhT2; Ws1 = H1P; n1 = 11; }
  } else {
    H = HH3; HP = H3P;
    bi = gbi3; bh = gbh3;
    hfP = h3f + (size_t)prv * BB * H3P; hfC = h3f + (size_t)cur * BB * H3P;
    hbC = h3b + (size_t)cur * BB * H3P;
    if (wgrp == 0) {
      A0 = h2b + (size_t)prv * BB * H1P; As0 = H1P; W0 = WiT3; Ws0 = H1P; n0 = 11;
      A1 = h3b + (size_t)prv * BB * H3P; As1 = H3P; W1p = WhT3; Ws1 = H3P; n1 = 2; k1off = 0;
    } else {
      A1 = h3b + (size_t)prv * BB * H3P; As1 = H3P; W1p = WhT3; Ws1 = H3P; n1 = 13; k1off = 128;
    }
  }
  const int r0 = rr * 64, j0 = cc * 64;

  f32x4 acc[4][2][2];
  {
    f32x4 z4 = {0.f, 0.f, 0.f, 0.f};
    for (int g = 0; g < 4; ++g) for (int a = 0; a < 2; ++a) for (int b = 0; b < 2; ++b) acc[g][a][b] = z4;
  }

  gru_pipe(A0, As0, W0, Ws0, A1, As1, W1p, Ws1, H, n0, n1, k1off,
           r0, j0, g0, g1, ltid, wr, wc, m16, kg, acc);

  if (ksplit) {
    __syncthreads();
    float* red = (float*)smem;
    if (wgrp == 1) {
      float* b = red + ltid * 64;
      #pragma unroll
      for (int g = 0; g < 4; ++g)
        #pragma unroll
        for (int fm = 0; fm < 2; ++fm)
          #pragma unroll
          for (int fn = 0; fn < 2; ++fn)
            *(f32x4*)(b + ((g * 2 + fm) * 2 + fn) * 4) = acc[g][fm][fn];
    }
    __syncthreads();
    if (wgrp == 1) return;
    {
      const float* b = red + ltid * 64;
      #pragma unroll
      for (int g = 0; g < 4; ++g)
        #pragma unroll
        for (int fm = 0; fm < 2; ++fm)
          #pragma unroll
          for (int fn = 0; fn < 2; ++fn)
            acc[g][fm][fn] += *(const f32x4*)(b + ((g * 2 + fm) * 2 + fn) * 4);
    }
  }

  // ---- gate epilogue (f32 carry) ----
  #pragma unroll
  for (int fn = 0; fn < 2; ++fn) {
    int j = j0 + wc * 32 + fn * 16 + m16;
    if (j >= H) continue;
    float bhz = bh[j], bhr = bh[H + j], bhh = bh[2 * H + j];
    float biz = 0.f, bir = 0.f, bih = 0.f;
    if (L != 0) { biz = bi[j]; bir = bi[H + j]; bih = bi[2 * H + j]; }
    #pragma unroll
    for (int fm = 0; fm < 2; ++fm) {
      #pragma unroll
      for (int ii = 0; ii < 4; ++ii) {
        int row = r0 + wr * 32 + fm * 16 + kg * 4 + ii;
        float az  = acc[0][fm][fn][ii];
        float ar  = acc[1][fm][fn][ii];
        float axh = acc[2][fm][fn][ii];
        float arh = acc[3][fm][fn][ii];
        float pz, pr, xh_, rh_;
        if (L == 0) {
          const float* xr_ = xp1 + (size_t)row * 2112;
          pz  = xr_[j] + az + bhz;
          pr  = xr_[HH1 + j] + ar + bhr;
          xh_ = xr_[2 * HH1 + j];
          rh_ = arh + bhh;
        } else {
          pz  = az + biz + bhz;
          pr  = ar + bir + bhr;
          xh_ = axh + bih;
          rh_ = arh + bhh;
        }
        float zg = 1.f / (1.f + expf(-pz));
        float rg = 1.f / (1.f + expf(-pr));
        float hh = tanhf(xh_ + rg * rh_);
        float hp = hfP[(size_t)row * HP + j];
        float hn = zg * hp + (1.f - zg) * hh;
        hfC[(size_t)row * HP + j] = hn;
        hbC[(size_t)row * HP + j] = f2b(hn);
      }
    }
  }
}

// ---------------- host ----------------
extern "C" void kernel_launch(void* const* d_in, const int* in_sizes, int n_in,
                              void* d_out, int out_size, void* d_ws, size_t ws_size,
                              hipStream_t stream)
{
  const float* z    = (const float*)d_in[0];
  const float* W1   = (const float*)d_in[1];
  const float* b1   = (const float*)d_in[2];
  const float* gWi1 = (const float*)d_in[3];
  const float* gWh1 = (const float*)d_in[4];
  const float* gbi1 = (const float*)d_in[5];
  const float* gbh1 = (const float*)d_in[6];
  const float* gWi2 = (const float*)d_in[7];
  const float* gWh2 = (const float*)d_in[8];
  const float* gbi2 = (const float*)d_in[9];
  const float* gbh2 = (const float*)d_in[10];
  const float* gWi3 = (const float*)d_in[11];
  const float* gWh3 = (const float*)d_in[12];
  const float* gbi3 = (const float*)d_in[13];
  const float* gbh3 = (const float*)d_in[14];
  const float* Wo   = (const float*)d_in[15];
  const float* bo   = (const float*)d_in[16];

  char* ws = (char*)d_ws;
  float* x_f  = (float*)(ws + O_X);
  float* xp1  = (float*)(ws + O_XP1);
  float* h1f  = (float*)(ws + O_H1F);
  float* h2f  = (float*)(ws + O_H2F);
  float* h3f  = (float*)(ws + O_H3F);
  u16*   h1b  = (u16*)(ws + O_H1B);
  u16*   h2b  = (u16*)(ws + O_H2B);
  u16*   h3b  = (u16*)(ws + O_H3B);
  u16*   WhT1 = (u16*)(ws + O_WHT1);
  u16*   WiT2 = (u16*)(ws + O_WIT2);
  u16*   WhT2 = (u16*)(ws + O_WHT2);
  u16*   WiT3 = (u16*)(ws + O_WIT3);
  u16*   WhT3 = (u16*)(ws + O_WHT3);
  u16*   WoT  = (u16*)(ws + O_WOT);
  unsigned int* tab = (unsigned int*)(ws + O_TAB);

  hipFuncSetAttribute((const void*)k_wave,
                      hipFuncAttributeMaxDynamicSharedMemorySize, 131072);

  hipMemsetAsync(ws + O_H1F, 0, ZERO_BYTES, stream);

  k_maketab<<<1, 64, 0, stream>>>(tab);
  k_selu<<<(BB * LAT + 255) / 256, 256, 0, stream>>>(z, W1, b1, x_f);
  k_xp1<<<9 * 64, 256, 0, stream>>>(x_f, gWi1, gbi1, xp1);

  k_transpose<<<11 * 33, 256, 0, stream>>>(gWh1, WhT1, 701, 2103, 704, 2112);
  k_transpose<<<11 * 33, 256, 0, stream>>>(gWi2, WiT2, 701, 2103, 704, 2112);
  k_transpose<<<11 * 33, 256, 0, stream>>>(gWh2, WhT2, 701, 2103, 704, 2112);
  k_transpose<<<11 * 44, 256, 0, stream>>>(gWi3, WiT3, 701, 2703, 704, 2816);
  k_transpose<<<15 * 44, 256, 0, stream>>>(gWh3, WhT3, 901, 2703, 960, 2816);
  k_transpose<<<15 * 1, 256, 0, stream>>>(Wo, WoT, 901, 35, 960, 64);

  for (int s = 0; s < TT + 3; ++s)
    k_wave<<<256, 512, 131072, stream>>>(s, tab, WhT1, WiT2, WhT2, WiT3, WhT3, WoT, xp1,
                                         gbh1, gbi2, gbh2, gbi3, gbh3, bo,
                                         h1f, h1b, h2f, h2b, h3f, h3b, (float*)d_out);
}

// Round 9
// 4982.994 us; speedup vs baseline: 1.7960x; 1.7769x over previous
//
#include <hip/hip_runtime.h>
#include <hip/hip_bf16.h>
#include <math.h>

typedef unsigned short u16;
typedef __attribute__((ext_vector_type(4))) float f32x4;
typedef __attribute__((ext_vector_type(8))) short s16x8;

#define BB  512
#define TT  120
#define LAT 292
#define HH1 701
#define HH3 901
#define H1P 704
#define H3P 960
#define CH  35

// ws layout (bytes)
static const size_t O_X    = 0;                     // 512*292*4
static const size_t O_XP1  = 598016;                // 512*2112*4 (f32)
static const size_t O_H1F  = 4923392;               // 2*512*704*4
static const size_t O_H2F  = 7806976;               // 2*512*704*4
static const size_t O_H3F  = 10690560;              // 2*512*960*4
static const size_t O_H1B  = 14622720;              // 2*512*704*2
static const size_t O_H2B  = 16064512;              // 2*512*704*2
static const size_t O_H3B  = 17506304;              // 2*512*960*2
static const size_t O_WHT1 = 19472384;              // 2112*704*2
static const size_t O_WIT2 = 22446080;              // 2112*704*2
static const size_t O_WHT2 = 25419776;              // 2112*704*2
static const size_t O_WIT3 = 28393472;              // 2816*704*2
static const size_t O_WHT3 = 32358400;              // 2816*960*2
static const size_t O_WOT  = 37765120;              // 64*960*2
static const size_t O_TAB  = 37888000;              // 256*4
static const size_t ZERO_BYTES = 14548992;          // O_H1F..O_H3B end

#define DSWZ(row, g) ((((g) ^ ((row) & 7)) << 4))

static __device__ __forceinline__ u16 f2b(float f){
  union { float f; unsigned int i; } v; v.f = f;
  unsigned int x = v.i;
  return (u16)((x + 0x7FFFu + ((x >> 16) & 1u)) >> 16);
}

// async 16B global->LDS (lds dst = wave-uniform base + lane*16)
#define GLL16(g, l) __builtin_amdgcn_global_load_lds( \
    (const __attribute__((address_space(1))) unsigned int*)(g), \
    (__attribute__((address_space(3))) unsigned int*)(l), 16, 0, 0)

// ---------------- prologue: x = selu(z @ W1 + b1) ----------------
__launch_bounds__(256)
__global__ void k_selu(const float* __restrict__ z, const float* __restrict__ W1,
                       const float* __restrict__ b1, float* __restrict__ x)
{
  int idx = blockIdx.x * 256 + threadIdx.x;
  if (idx >= BB * LAT) return;
  int b = idx / LAT, i = idx - b * LAT;
  float acc = b1[i];
  const float* zr = z + (size_t)b * LAT;
  for (int k = 0; k < LAT; ++k)
    acc += zr[k] * W1[k * LAT + i];
  const float alpha = 1.6732632423543772f, scale = 1.0507009873554805f;
  x[idx] = scale * (acc > 0.f ? acc : alpha * (expf(acc) - 1.f));
}

// ---------------- prologue: xp1 = x @ Wi1 + bi1 (f32, [512][2112]) ----------------
__launch_bounds__(256)
__global__ void k_xp1(const float* __restrict__ x, const float* __restrict__ Wi1,
                      const float* __restrict__ bi1, float* __restrict__ xp1)
{
  int nb = blockIdx.x % 9, bb = blockIdx.x / 9;
  int n = nb * 256 + threadIdx.x;
  int b0 = bb * 8;
  if (n >= 2112) return;
  if (n >= 2103) { for (int r = 0; r < 8; ++r) xp1[(size_t)(b0 + r) * 2112 + n] = 0.f; return; }
  float bias = bi1[n];
  float acc[8];
  for (int r = 0; r < 8; ++r) acc[r] = bias;
  for (int k = 0; k < LAT; ++k) {
    float w = Wi1[(size_t)k * 2103 + n];
    #pragma unroll
    for (int r = 0; r < 8; ++r) acc[r] += x[(size_t)(b0 + r) * LAT + k] * w;
  }
  for (int r = 0; r < 8; ++r) xp1[(size_t)(b0 + r) * 2112 + n] = acc[r];
}

// ---------------- prologue: WT[n][k] = bf16(W[k][n]), zero-padded ----------------
__launch_bounds__(256)
__global__ void k_transpose(const float* __restrict__ W, u16* __restrict__ WT,
                            int K, int N, int Kpad, int RowsPad)
{
  int tilesN = RowsPad / 64;
  int tk = blockIdx.x / tilesN, tn = blockIdx.x % tilesN;
  int k0 = tk * 64, n0 = tn * 64;
  __shared__ u16 lds[64][72];
  int tid = threadIdx.x;
  int nl = tid & 63, q = tid >> 6;
  for (int i = 0; i < 16; ++i) {
    int kl = q * 16 + i;
    int k = k0 + kl, n = n0 + nl;
    lds[kl][nl] = (k < K && n < N) ? f2b(W[(size_t)k * N + n]) : (u16)0;
  }
  __syncthreads();
  for (int i = 0; i < 16; ++i) {
    int rl = q * 16 + i;
    WT[(size_t)(n0 + rl) * Kpad + k0 + nl] = lds[nl][rl];
  }
}

// ---------------- prologue: 256 balanced 512-thread blocks, XCD col-pinned ----
__global__ void k_maketab(unsigned int* __restrict__ tab)
{
  if (threadIdx.x != 0 || blockIdx.x != 0) return;
  for (int x = 0; x < 8; ++x) {
    for (int li = 0; li < 32; ++li) {
      unsigned v;
      if (li < 15) {            // GRU3 ksplit
        int t3 = 15 * x + li;
        v = 0xFFFF0000u | (2u << 12) | ((unsigned)(t3 & 7) << 8) | (unsigned)(t3 >> 3);
      } else if (li < 26) {     // GRU2 ksplit
        int t2 = 11 * x + (li - 15);
        v = 0xFFFF0000u | (1u << 12) | ((unsigned)(t2 & 7) << 8) | (unsigned)(t2 >> 3);
      } else if (li < 31) {     // GRU1 pairs
        int pi = 5 * x + (li - 26);
        int i0 = 2 * pi, i1 = 2 * pi + 1;
        unsigned lo = ((unsigned)(i0 & 7) << 8) | (unsigned)(i0 >> 3);
        unsigned hw = ((unsigned)(i1 & 7) << 8) | (unsigned)(i1 >> 3);
        v = lo | (hw << 16);
      } else {
        if (x < 4) {            // OUT pairs
          unsigned lo = (3u << 12) | ((unsigned)(2 * x) << 8);
          unsigned hw = (3u << 12) | ((unsigned)(2 * x + 1) << 8);
          v = lo | (hw << 16);
        } else {                // leftover GRU1 pairs
          int pi = 40 + (x - 4);
          int i0 = 2 * pi, i1 = 2 * pi + 1;
          unsigned lo = ((unsigned)(i0 & 7) << 8) | (unsigned)(i0 >> 3);
          unsigned hw = ((unsigned)(i1 & 7) << 8) | (unsigned)(i1 >> 3);
          v = lo | (hw << 16);
        }
      }
      tab[x + 8 * li] = v;
    }
  }
}

// ---------------- staged-chunk: async global_load_lds, pre-swizzled source ----------------
// buffer layout (32KB, linear slots of 16B): A: slots 0..511 (row=s>>3, gl=s&7),
// B: slots 512..2047 (gate=(s-512)>>9, col, gl). Linear slot holds granule
// gq = gl ^ (row&7)  ->  read side uses DSWZ as before.

static __device__ __forceinline__ void stage_gru(
    const u16* __restrict__ A, int As, const u16* __restrict__ W, int Ws, int WH,
    int r0, int j0, int kbase, int wl, int lane, char* buf)
{
  #pragma unroll
  for (int i = 0; i < 8; ++i) {
    int slot = wl * 512 + i * 64 + lane;
    const u16* g;
    if (slot < 512) {                         // wave 0 only (uniform per wave)
      int row = slot >> 3, gl = slot & 7;
      int gq = gl ^ (row & 7);
      g = A + (size_t)(r0 + row) * As + kbase + gq * 8;
    } else {                                  // waves 1..3
      int s2 = slot - 512;
      int gate = s2 >> 9, loc = s2 & 511;
      int col = loc >> 3, gl = loc & 7;
      int gq = gl ^ (col & 7);
      g = W + ((size_t)gate * WH + j0 + col) * Ws + kbase + gq * 8;
    }
    char* l = buf + (wl * 512 + i * 64) * 16; // wave-uniform LDS base
    GLL16(g, l);
  }
}

template<int HACC>
static __device__ __forceinline__ void mm_gru(const char* gb, int wr, int wc, int m16, int kg,
                                              f32x4 (&acc)[4][2][2])
{
  #pragma unroll
  for (int s = 0; s < 2; ++s) {
    s16x8 af[2];
    #pragma unroll
    for (int fm = 0; fm < 2; ++fm) {
      int row = wr * 32 + fm * 16 + m16;
      af[fm] = *(const s16x8*)(gb + row * 128 + DSWZ(row, s * 4 + kg));
    }
    #pragma unroll
    for (int g = 0; g < 3; ++g) {
      #pragma unroll
      for (int fn = 0; fn < 2; ++fn) {
        int col = wc * 32 + fn * 16 + m16;
        s16x8 bf = *(const s16x8*)(gb + 8192 + g * 8192 + col * 128 + DSWZ(col, s * 4 + kg));
        const int ai = (g == 2) ? HACC : g;
        #pragma unroll
        for (int fm = 0; fm < 2; ++fm)
          acc[ai][fm][fn] = __builtin_amdgcn_mfma_f32_16x16x32_bf16(af[fm], bf, acc[ai][fm][fn], 0, 0, 0);
      }
    }
  }
}

// two-segment GRU pipeline: double-buffered LDS, async staging, one barrier/chunk
static __device__ __forceinline__ void gru_pipe(
    const u16* A0, int As0, const u16* W0, int Ws0,
    const u16* A1, int As1, const u16* W1p, int Ws1,
    int WH, int n0, int n1, int k1off,
    int r0, int j0, char* g0, char* g1, int wl, int lane,
    int wr, int wc, int m16, int kg, f32x4 (&acc)[4][2][2])
{
  const int n = n0 + n1;
#define STG(C, BUF) do { int c_ = (C); \
    if (c_ < n0) stage_gru(A0, As0, W0, Ws0, WH, r0, j0, c_ * 64, wl, lane, (BUF)); \
    else         stage_gru(A1, As1, W1p, Ws1, WH, r0, j0, (c_ - n0) * 64 + k1off, wl, lane, (BUF)); \
  } while (0)
  STG(0, g0);
  __syncthreads();
  for (int ch = 0; ch < n; ch += 2) {
    if (ch + 1 < n) STG(ch + 1, g1);
    if (ch < n0) mm_gru<2>(g0, wr, wc, m16, kg, acc);
    else         mm_gru<3>(g0, wr, wc, m16, kg, acc);
    __syncthreads();
    if (ch + 1 >= n) break;
    if (ch + 2 < n) STG(ch + 2, g0);
    if (ch + 1 < n0) mm_gru<2>(g1, wr, wc, m16, kg, acc);
    else             mm_gru<3>(g1, wr, wc, m16, kg, acc);
    __syncthreads();
  }
#undef STG
}

// ---------------- wavefront step kernel: 256 blocks x 512 threads, 128KB LDS ----------------
__launch_bounds__(512, 2)
__global__ void k_wave(int s, const unsigned int* __restrict__ tab,
    const u16* __restrict__ WhT1, const u16* __restrict__ WiT2, const u16* __restrict__ WhT2,
    const u16* __restrict__ WiT3, const u16* __restrict__ WhT3, const u16* __restrict__ WoT,
    const float* __restrict__ xp1,
    const float* __restrict__ gbh1,
    const float* __restrict__ gbi2, const float* __restrict__ gbh2,
    const float* __restrict__ gbi3, const float* __restrict__ gbh3,
    const float* __restrict__ bo,
    float* __restrict__ h1f, u16* __restrict__ h1b,
    float* __restrict__ h2f, u16* __restrict__ h2b,
    float* __restrict__ h3f, u16* __restrict__ h3b,
    float* __restrict__ out)
{
  extern __shared__ __align__(16) char smem[];      // 131072 dynamic
  const int tid  = threadIdx.x;
  const int wgrp = tid >> 8;
  const int ltid = tid & 255;
  const int lane = tid & 63;
  const int wl   = (tid >> 6) & 3;
  const int wr = wl >> 1, wc = wl & 1;
  const int m16 = lane & 15, kg = lane >> 4;
  char* g0 = smem + wgrp * 65536;
  char* g1 = g0 + 32768;

  const unsigned e  = tab[blockIdx.x];
  const unsigned lo = e & 0xFFFFu, hi = e >> 16;
  const bool ksplit = (hi == 0xFFFFu);
  const unsigned item = (!ksplit && wgrp == 1) ? hi : lo;
  const int L  = (item >> 12) & 3;
  const int rr = (item >> 8) & 0xF;
  const int cc = item & 0xFF;
  const int t = s - L;
  if (t < 0 || t >= TT) return;
  const int cur = s & 1, prv = cur ^ 1;

  if (L == 3) {
    // ---- output projection + softmax (each wave-group one 64-row tile) ----
    const int r0 = rr * 64;
    const u16* Ab = h3b + (size_t)prv * BB * H3P;
    f32x4 acc2[2][2];
    { f32x4 z4 = {0.f,0.f,0.f,0.f}; for (int a=0;a<2;++a) for (int b=0;b<2;++b) acc2[a][b]=z4; }
    int4 ra[2], rb2[2];
    const int n = H3P / 64;                 // 15 chunks
    #pragma unroll
    for (int it = 0; it < 2; ++it) {
      int gi = it * 256 + ltid; int r = gi >> 3, gq = gi & 7;
      ra[it]  = *(const int4*)(Ab + (size_t)(r0 + r) * H3P + gq * 8);
      rb2[it] = *(const int4*)(WoT + (size_t)r * H3P + gq * 8);
    }
    #pragma unroll
    for (int it = 0; it < 2; ++it) {
      int gi = it * 256 + ltid; int r = gi >> 3, gq = gi & 7;
      *(int4*)(g0 + r * 128 + DSWZ(r, gq)) = ra[it];
      *(int4*)(g0 + 8192 + r * 128 + DSWZ(r, gq)) = rb2[it];
    }
    __syncthreads();
    for (int ch = 0; ch < n; ++ch) {
      const bool have = (ch + 1 < n);
      if (have) {
        int kb = (ch + 1) * 64;
        #pragma unroll
        for (int it = 0; it < 2; ++it) {
          int gi = it * 256 + ltid; int r = gi >> 3, gq = gi & 7;
          ra[it]  = *(const int4*)(Ab + (size_t)(r0 + r) * H3P + kb + gq * 8);
          rb2[it] = *(const int4*)(WoT + (size_t)r * H3P + kb + gq * 8);
        }
      }
      #pragma unroll
      for (int s2 = 0; s2 < 2; ++s2) {
        s16x8 af[2], bf[2];
        #pragma unroll
        for (int fm = 0; fm < 2; ++fm) {
          int row = wr * 32 + fm * 16 + m16;
          af[fm] = *(const s16x8*)(g0 + row * 128 + DSWZ(row, s2 * 4 + kg));
        }
        #pragma unroll
        for (int fn = 0; fn < 2; ++fn) {
          int col = wc * 32 + fn * 16 + m16;
          bf[fn] = *(const s16x8*)(g0 + 8192 + col * 128 + DSWZ(col, s2 * 4 + kg));
        }
        #pragma unroll
        for (int fm = 0; fm < 2; ++fm)
          #pragma unroll
          for (int fn = 0; fn < 2; ++fn)
            acc2[fm][fn] = __builtin_amdgcn_mfma_f32_16x16x32_bf16(af[fm], bf[fn], acc2[fm][fn], 0, 0, 0);
      }
      if (have) {
        __syncthreads();
        #pragma unroll
        for (int it = 0; it < 2; ++it) {
          int gi = it * 256 + ltid; int r = gi >> 3, gq = gi & 7;
          *(int4*)(g0 + r * 128 + DSWZ(r, gq)) = ra[it];
          *(int4*)(g0 + 8192 + r * 128 + DSWZ(r, gq)) = rb2[it];
        }
        __syncthreads();
      }
    }
    __syncthreads();
    float (*ldsL)[68] = (float (*)[68])g0;
    #pragma unroll
    for (int fn = 0; fn < 2; ++fn) {
      int col = wc * 32 + fn * 16 + m16;
      float bov = (col < CH) ? bo[col] : 0.f;
      #pragma unroll
      for (int fm = 0; fm < 2; ++fm)
        #pragma unroll
        for (int ii = 0; ii < 4; ++ii)
          ldsL[wr * 32 + fm * 16 + kg * 4 + ii][col] = acc2[fm][fn][ii] + bov;
    }
    __syncthreads();
    if (ltid < 64) {
      int b = r0 + ltid;
      float mx = -1e30f;
      for (int c2 = 0; c2 < CH; ++c2) mx = fmaxf(mx, ldsL[ltid][c2]);
      float sum = 0.f;
      for (int c2 = 0; c2 < CH; ++c2) sum += expf(ldsL[ltid][c2] - mx);
      float inv = 1.f / sum;
      size_t ob = ((size_t)b * TT + t) * CH;
      for (int c2 = 0; c2 < CH; ++c2) out[ob + c2] = expf(ldsL[ltid][c2] - mx) * inv;
    }
    return;
  }

  // ---- GRU tile config ----
  int H, HP;
  const u16 *A0 = nullptr, *W0 = nullptr, *A1 = nullptr, *W1p = nullptr;
  int As0 = 0, Ws0 = 0, As1 = 0, Ws1 = 0, n0 = 0, n1 = 0, k1off = 0;
  const float *bi = nullptr, *bh;
  float *hfP, *hfC; u16 *hbC;
  if (L == 0) {
    H = HH1; HP = H1P;
    A1 = h1b + (size_t)prv * BB * H1P; As1 = H1P; W1p = WhT1; Ws1 = H1P; n1 = 11;
    bh = gbh1;
    hfP = h1f + (size_t)prv * BB * H1P; hfC = h1f + (size_t)cur * BB * H1P;
    hbC = h1b + (size_t)cur * BB * H1P;
  } else if (L == 1) {
    H = HH1; HP = H1P;
    bi = gbi2; bh = gbh2;
    hfP = h2f + (size_t)prv * BB * H1P; hfC = h2f + (size_t)cur * BB * H1P;
    hbC = h2b + (size_t)cur * BB * H1P;
    if (wgrp == 0) { A0 = h1b + (size_t)prv * BB * H1P; As0 = H1P; W0 = WiT2; Ws0 = H1P; n0 = 11; }
    else           { A1 = h2b + (size_t)prv * BB * H1P; As1 = H1P; W1p = WhT2; Ws1 = H1P; n1 = 11; }
  } else {
    H = HH3; HP = H3P;
    bi = gbi3; bh = gbh3;
    hfP = h3f + (size_t)prv * BB * H3P; hfC = h3f + (size_t)cur * BB * H3P;
    hbC = h3b + (size_t)cur * BB * H3P;
    if (wgrp == 0) {
      A0 = h2b + (size_t)prv * BB * H1P; As0 = H1P; W0 = WiT3; Ws0 = H1P; n0 = 11;
      A1 = h3b + (size_t)prv * BB * H3P; As1 = H3P; W1p = WhT3; Ws1 = H3P; n1 = 2; k1off = 0;
    } else {
      A1 = h3b + (size_t)prv * BB * H3P; As1 = H3P; W1p = WhT3; Ws1 = H3P; n1 = 13; k1off = 128;
    }
  }
  const int r0 = rr * 64, j0 = cc * 64;

  f32x4 acc[4][2][2];
  {
    f32x4 z4 = {0.f, 0.f, 0.f, 0.f};
    for (int g = 0; g < 4; ++g) for (int a = 0; a < 2; ++a) for (int b = 0; b < 2; ++b) acc[g][a][b] = z4;
  }

  gru_pipe(A0, As0, W0, Ws0, A1, As1, W1p, Ws1, H, n0, n1, k1off,
           r0, j0, g0, g1, wl, lane, wr, wc, m16, kg, acc);

  if (ksplit) {
    __syncthreads();
    float* red = (float*)smem;
    if (wgrp == 1) {
      float* b = red + ltid * 64;
      #pragma unroll
      for (int g = 0; g < 4; ++g)
        #pragma unroll
        for (int fm = 0; fm < 2; ++fm)
          #pragma unroll
          for (int fn = 0; fn < 2; ++fn)
            *(f32x4*)(b + ((g * 2 + fm) * 2 + fn) * 4) = acc[g][fm][fn];
    }
    __syncthreads();
    if (wgrp == 1) return;
    {
      const float* b = red + ltid * 64;
      #pragma unroll
      for (int g = 0; g < 4; ++g)
        #pragma unroll
        for (int fm = 0; fm < 2; ++fm)
          #pragma unroll
          for (int fn = 0; fn < 2; ++fn)
            acc[g][fm][fn] += *(const f32x4*)(b + ((g * 2 + fm) * 2 + fn) * 4);
    }
  }

  // ---- gate epilogue (f32 carry) ----
  #pragma unroll
  for (int fn = 0; fn < 2; ++fn) {
    int j = j0 + wc * 32 + fn * 16 + m16;
    if (j >= H) continue;
    float bhz = bh[j], bhr = bh[H + j], bhh = bh[2 * H + j];
    float biz = 0.f, bir = 0.f, bih = 0.f;
    if (L != 0) { biz = bi[j]; bir = bi[H + j]; bih = bi[2 * H + j]; }
    #pragma unroll
    for (int fm = 0; fm < 2; ++fm) {
      #pragma unroll
      for (int ii = 0; ii < 4; ++ii) {
        int row = r0 + wr * 32 + fm * 16 + kg * 4 + ii;
        float az  = acc[0][fm][fn][ii];
        float ar  = acc[1][fm][fn][ii];
        float axh = acc[2][fm][fn][ii];
        float arh = acc[3][fm][fn][ii];
        float pz, pr, xh_, rh_;
        if (L == 0) {
          const float* xr_ = xp1 + (size_t)row * 2112;
          pz  = xr_[j] + az + bhz;
          pr  = xr_[HH1 + j] + ar + bhr;
          xh_ = xr_[2 * HH1 + j];
          rh_ = arh + bhh;
        } else {
          pz  = az + biz + bhz;
          pr  = ar + bir + bhr;
          xh_ = axh + bih;
          rh_ = arh + bhh;
        }
        float zg = 1.f / (1.f + expf(-pz));
        float rg = 1.f / (1.f + expf(-pr));
        float hh = tanhf(xh_ + rg * rh_);
        float hp = hfP[(size_t)row * HP + j];
        float hn = zg * hp + (1.f - zg) * hh;
        hfC[(size_t)row * HP + j] = hn;
        hbC[(size_t)row * HP + j] = f2b(hn);
      }
    }
  }
}

// ---------------- host ----------------
extern "C" void kernel_launch(void* const* d_in, const int* in_sizes, int n_in,
                              void* d_out, int out_size, void* d_ws, size_t ws_size,
                              hipStream_t stream)
{
  const float* z    = (const float*)d_in[0];
  const float* W1   = (const float*)d_in[1];
  const float* b1   = (const float*)d_in[2];
  const float* gWi1 = (const float*)d_in[3];
  const float* gWh1 = (const float*)d_in[4];
  const float* gbi1 = (const float*)d_in[5];
  const float* gbh1 = (const float*)d_in[6];
  const float* gWi2 = (const float*)d_in[7];
  const float* gWh2 = (const float*)d_in[8];
  const float* gbi2 = (const float*)d_in[9];
  const float* gbh2 = (const float*)d_in[10];
  const float* gWi3 = (const float*)d_in[11];
  const float* gWh3 = (const float*)d_in[12];
  const float* gbi3 = (const float*)d_in[13];
  const float* gbh3 = (const float*)d_in[14];
  const float* Wo   = (const float*)d_in[15];
  const float* bo   = (const float*)d_in[16];

  char* ws = (char*)d_ws;
  float* x_f  = (float*)(ws + O_X);
  float* xp1  = (float*)(ws + O_XP1);
  float* h1f  = (float*)(ws + O_H1F);
  float* h2f  = (float*)(ws + O_H2F);
  float* h3f  = (float*)(ws + O_H3F);
  u16*   h1b  = (u16*)(ws + O_H1B);
  u16*   h2b  = (u16*)(ws + O_H2B);
  u16*   h3b  = (u16*)(ws + O_H3B);
  u16*   WhT1 = (u16*)(ws + O_WHT1);
  u16*   WiT2 = (u16*)(ws + O_WIT2);
  u16*   WhT2 = (u16*)(ws + O_WHT2);
  u16*   WiT3 = (u16*)(ws + O_WIT3);
  u16*   WhT3 = (u16*)(ws + O_WHT3);
  u16*   WoT  = (u16*)(ws + O_WOT);
  unsigned int* tab = (unsigned int*)(ws + O_TAB);

  hipFuncSetAttribute((const void*)k_wave,
                      hipFuncAttributeMaxDynamicSharedMemorySize, 131072);

  hipMemsetAsync(ws + O_H1F, 0, ZERO_BYTES, stream);

  k_maketab<<<1, 64, 0, stream>>>(tab);
  k_selu<<<(BB * LAT + 255) / 256, 256, 0, stream>>>(z, W1, b1, x_f);
  k_xp1<<<9 * 64, 256, 0, stream>>>(x_f, gWi1, gbi1, xp1);

  k_transpose<<<11 * 33, 256, 0, stream>>>(gWh1, WhT1, 701, 2103, 704, 2112);
  k_transpose<<<11 * 33, 256, 0, stream>>>(gWi2, WiT2, 701, 2103, 704, 2112);
  k_transpose<<<11 * 33, 256, 0, stream>>>(gWh2, WhT2, 701, 2103, 704, 2112);
  k_transpose<<<11 * 44, 256, 0, stream>>>(gWi3, WiT3, 701, 2703, 704, 2816);
  k_transpose<<<15 * 44, 256, 0, stream>>>(gWh3, WhT3, 901, 2703, 960, 2816);
  k_transpose<<<15 * 1, 256, 0, stream>>>(Wo, WoT, 901, 35, 960, 64);

  for (int s = 0; s < TT + 3; ++s)
    k_wave<<<256, 512, 131072, stream>>>(s, tab, WhT1, WiT2, WhT2, WiT3, WhT3, WoT, xp1,
                                         gbh1, gbi2, gbh2, gbi3, gbh3, bo,
                                         h1f, h1b, h2f, h2b, h3f, h3b, (float*)d_out);
}